// Round 11
// baseline (301.751 us; speedup 1.0000x reference)
//
#include <hip/hip_runtime.h>
#include <math.h>

#define NTT 365
#define NSS 300
#define NROWS (NTT*NSS)   // 109500
#define TROWS 416         // padded time rows for PT and NV (max prefetch index 415)

using bf16x8 = __attribute__((ext_vector_type(8))) short;
using f32x4  = __attribute__((ext_vector_type(4))) float;

__device__ __forceinline__ float sigf(float v) { return 1.0f / (1.0f + __expf(-v)); }

__device__ __forceinline__ float tanhfast(float x) {
    float e = __expf(2.0f * x);
    return 1.0f - 2.0f * __builtin_amdgcn_rcpf(1.0f + e);
}

__device__ __forceinline__ unsigned short f2bf(float f) {
    unsigned u = __builtin_bit_cast(unsigned, f);
    u += 0x7FFFu + ((u >> 16) & 1u);
    return (unsigned short)(u >> 16);
}

// ---------------- K0: swizzle fcT weights to fragment-major bf16 ----------------
__global__ __launch_bounds__(256) void k_prep(const float* __restrict__ w1,
                                              const float* __restrict__ w2,
                                              unsigned short* __restrict__ w1s,
                                              unsigned short* __restrict__ w2s)
{
    int G = blockIdx.x * 256 + threadIdx.x;
    if (G < 2048) {
        int lane = G & 63, ks = (G >> 6) & 1, tile = G >> 7;
        int o = tile * 16 + (lane & 15);
        int kb = ks * 32 + (lane >> 4) * 8;
        unsigned short tmp[8];
#pragma unroll
        for (int e = 0; e < 8; ++e) {
            int k = kb + e;
            tmp[e] = (k < 38) ? f2bf(w1[o * 38 + k]) : (unsigned short)0;
        }
        *(bf16x8*)(w1s + (size_t)G * 8) = *(bf16x8*)tmp;
    } else if (G < 2048 + 12288) {
        int G2 = G - 2048;
        int lane = G2 & 63, ks = (G2 >> 6) & 7, tile = G2 >> 9;
        int o = tile * 16 + (lane & 15);
        int kb = ks * 32 + (lane >> 4) * 8;
        unsigned short tmp[8];
#pragma unroll
        for (int e = 0; e < 8; ++e) tmp[e] = f2bf(w2[o * 256 + kb + e]);
        *(bf16x8*)(w2s + (size_t)G2 * 8) = *(bf16x8*)tmp;
    }
}

// ---------------- K1: per-site MLPs, output-sliced grid (30 x 8) ----------------
__global__ __launch_bounds__(256) void k_site(
    const float* __restrict__ xc,
    const float* __restrict__ wW1, const float* __restrict__ bW1,
    const float* __restrict__ wW2, const float* __restrict__ bW2,
    const float* __restrict__ wR1, const float* __restrict__ bR1,
    const float* __restrict__ wR2, const float* __restrict__ bR2,
    float* __restrict__ wsite, float* __restrict__ rsite)
{
    __shared__ float xcb[10][32];
    __shared__ float hW[10][256];
    __shared__ float hR[10][256];
    int tid = threadIdx.x;
    int s0 = blockIdx.x * 10;
    int os = blockIdx.y;
    for (int i = tid; i < 10 * 32; i += 256) xcb[i / 32][i % 32] = xc[s0 * 32 + i];
    __syncthreads();
    {
        int j = tid;
        float aW[10], aR[10];
#pragma unroll
        for (int r = 0; r < 10; ++r) { aW[r] = bW1[j]; aR[r] = bR1[j]; }
        for (int k = 0; k < 32; ++k) {
            float wv = wW1[j * 32 + k], rv = wR1[j * 32 + k];
#pragma unroll
            for (int r = 0; r < 10; ++r) { float xv = xcb[r][k]; aW[r] += xv * wv; aR[r] += xv * rv; }
        }
#pragma unroll
        for (int r = 0; r < 10; ++r) { hW[r][j] = tanhfast(aW[r]); hR[r][j] = tanhfast(aR[r]); }
    }
    __syncthreads();
    if (tid < 240) {
        int o_lin = os * 240 + tid;
        float acc[10];
        if (o_lin < 896) {
            int o = o_lin;
#pragma unroll
            for (int r = 0; r < 10; ++r) acc[r] = bW2[o];
            for (int k = 0; k < 256; ++k) {
                float wv = wW2[o * 256 + k];
#pragma unroll
                for (int r = 0; r < 10; ++r) acc[r] += hW[r][k] * wv;
            }
#pragma unroll
            for (int r = 0; r < 10; ++r) wsite[(s0 + r) * 896 + o] = acc[r];
        } else {
            int o = o_lin - 896;
#pragma unroll
            for (int r = 0; r < 10; ++r) acc[r] = bR2[o];
            for (int k = 0; k < 256; ++k) {
                float wv = wR2[o * 256 + k];
#pragma unroll
                for (int r = 0; r < 10; ++r) acc[r] += hR[r][k] * wv;
            }
#pragma unroll
            for (int r = 0; r < 10; ++r) rsite[(s0 + r) * 1024 + o] = acc[r];
        }
    }
}

// ---------------- K1b: softmax of ga over h per site ----------------
__global__ __launch_bounds__(128) void k_softmax_ga(const float* __restrict__ wsite,
                                                    float* __restrict__ ga)
{
    int s = blockIdx.x, tid = threadIdx.x;
    __shared__ float red[2];
    float v = wsite[s * 896 + 6 * 128 + tid];
    float m = v;
#pragma unroll
    for (int off = 32; off >= 1; off >>= 1) m = fmaxf(m, __shfl_xor(m, off));
    if ((tid & 63) == 0) red[tid >> 6] = m;
    __syncthreads();
    m = fmaxf(red[0], red[1]);
    __syncthreads();
    float e = __expf(v - m);
    float ssum = e;
#pragma unroll
    for (int off = 32; off >= 1; off >>= 1) ssum += __shfl_xor(ssum, off);
    if ((tid & 63) == 0) red[tid >> 6] = ssum;
    __syncthreads();
    ssum = red[0] + red[1];
    ga[s * 128 + tid] = e / ssum;
}

// ---------------- K1c: precompute ct gate params per (s,h) ----------------
__global__ __launch_bounds__(128) void k_ct(const float* __restrict__ xc,
                                            const float* __restrict__ ctw,
                                            const float* __restrict__ ctb,
                                            float* __restrict__ ctp8,
                                            float* __restrict__ ctpb)
{
    __shared__ float xcs[32];
    int s = blockIdx.x, h = threadIdx.x;
    if (h < 32) xcs[h] = xc[s * 32 + h];
    __syncthreads();
    const float L2E = 1.4426950408889634f;
    const float LG01 = -3.3219280948873623f;
    float out[8];
    float cgb = 0.0f;
#pragma unroll
    for (int g = 0; g < 3; ++g) {
        const float* wr = ctw + (g * 128 + h) * 34;
        float base = ctb[g * 128 + h];
        for (int k = 0; k < 32; ++k) base += wr[2 + k] * xcs[k];
        float w0 = wr[0] * L2E, w1 = wr[1] * L2E;
        float bb = base * L2E + ((g == 0) ? LG01 : 0.0f);
        if (g == 0) { out[0] = w0; out[1] = w1; out[2] = bb; }
        else if (g == 1) { out[3] = w0; out[4] = w1; out[5] = bb; }
        else { out[6] = w0; out[7] = w1; cgb = bb; }
    }
    float4* dst = (float4*)(ctp8 + ((size_t)s * 128 + h) * 8);
    dst[0] = make_float4(out[0], out[1], out[2], out[3]);
    dst[1] = make_float4(out[4], out[5], out[6], out[7]);
    ctpb[(size_t)s * 128 + h] = cgb;
}

// ---------------- K2: fcT MLP via bf16 MFMA -> PT[g] ([t][s]), NVu[t][s][h] ----------------
__global__ __launch_bounds__(512) void k_fcT(
    const float* __restrict__ x, const float* __restrict__ xc,
    const unsigned short* __restrict__ w1s, const float* __restrict__ b1,
    const unsigned short* __restrict__ w2s, const float* __restrict__ b2,
    float4* __restrict__ PT, unsigned* __restrict__ NVu)
{
    __shared__ unsigned short A1[64][72];
    __shared__ unsigned short hb[64][264];
    __shared__ float2 pfE[64];
    int tid = threadIdx.x;
    int row0 = blockIdx.x * 64;

    for (int idx = tid; idx < 64 * 64; idx += 512) {
        int r = idx >> 6, c = idx & 63;
        int g = row0 + r;
        float val = 0.0f;
        if (g < NROWS) {
            if (c < 6) val = x[g * 6 + c];
            else if (c < 38) { int s = g % NSS; val = xc[s * 32 + (c - 6)]; }
        }
        A1[r][c] = f2bf(val);
    }
    if (tid < 64) {
        int r = tid, g = row0 + r;
        float P = 0, E = 0, T1 = 0, T2 = 0;
        if (g < NROWS) { P = x[g * 6]; E = x[g * 6 + 1]; T1 = x[g * 6 + 2]; T2 = x[g * 6 + 3]; }
        float den = T2 - T1;
        float dg = (den == 0.0f) ? 1.0f : den;
        float ratio = fminf(fmaxf((T1 + T2) / dg, -1.0f), 1.0f);
        float vf = acosf(ratio) * (1.0f / 3.1415f);
        vf = (T1 >= 0.0f) ? 0.0f : ((T2 <= 0.0f) ? 1.0f : vf);
        pfE[r] = make_float2(P * (1.0f - vf), 2.0f * E);
        if (g < NROWS) PT[g] = make_float4(P * vf, T1, T2, vf);
    }
    __syncthreads();

    int lane = tid & 63, wv = tid >> 6;
    int r16 = lane & 15;
    int kg = (lane >> 4) * 8;
    int rq = (lane >> 4) * 4;

    {
        int mt = wv & 3, nb = (wv >> 2) * 8;
        f32x4 acc[8];
#pragma unroll
        for (int i = 0; i < 8; ++i) acc[i] = (f32x4){0.f, 0.f, 0.f, 0.f};
#pragma unroll
        for (int ks = 0; ks < 2; ++ks) {
            bf16x8 a = *(const bf16x8*)&A1[mt * 16 + r16][ks * 32 + kg];
#pragma unroll
            for (int i = 0; i < 8; ++i) {
                bf16x8 b = *(const bf16x8*)(w1s + ((size_t)(((nb + i) * 2 + ks) * 64 + lane) << 3));
                acc[i] = __builtin_amdgcn_mfma_f32_16x16x32_bf16(a, b, acc[i], 0, 0, 0);
            }
        }
#pragma unroll
        for (int i = 0; i < 8; ++i) {
            int col = (nb + i) * 16 + r16;
            float bias = b1[col];
#pragma unroll
            for (int j = 0; j < 4; ++j) {
                int row = mt * 16 + rq + j;
                hb[row][col] = f2bf(tanhfast(acc[i][j] + bias));
            }
        }
    }
    __syncthreads();

    {
        int t0 = wv, t1 = wv + 8, t2 = wv + 16;
        f32x4 acc[4][3];
#pragma unroll
        for (int m = 0; m < 4; ++m)
#pragma unroll
            for (int c = 0; c < 3; ++c) acc[m][c] = (f32x4){0.f, 0.f, 0.f, 0.f};
#pragma unroll
        for (int ks = 0; ks < 8; ++ks) {
            bf16x8 b0 = *(const bf16x8*)(w2s + ((size_t)((t0 * 8 + ks) * 64 + lane) << 3));
            bf16x8 b1v = *(const bf16x8*)(w2s + ((size_t)((t1 * 8 + ks) * 64 + lane) << 3));
            bf16x8 b2v = *(const bf16x8*)(w2s + ((size_t)((t2 * 8 + ks) * 64 + lane) << 3));
#pragma unroll
            for (int m = 0; m < 4; ++m) {
                bf16x8 a = *(const bf16x8*)&hb[m * 16 + r16][ks * 32 + kg];
                acc[m][0] = __builtin_amdgcn_mfma_f32_16x16x32_bf16(a, b0, acc[m][0], 0, 0, 0);
                acc[m][1] = __builtin_amdgcn_mfma_f32_16x16x32_bf16(a, b1v, acc[m][1], 0, 0, 0);
                acc[m][2] = __builtin_amdgcn_mfma_f32_16x16x32_bf16(a, b2v, acc[m][2], 0, 0, 0);
            }
        }
        int hcol = wv * 16 + r16;
        float bias0 = b2[hcol], bias1 = b2[128 + hcol], bias2 = b2[256 + hcol];
#pragma unroll
        for (int m = 0; m < 4; ++m) {
            float2 pf[4];
#pragma unroll
            for (int j = 0; j < 4; ++j) pf[j] = pfE[m * 16 + rq + j];
#pragma unroll
            for (int j = 0; j < 4; ++j) {
                int r = m * 16 + rq + j;
                int g = row0 + r;
                if (g < NROWS) {
                    float vi = fminf(fmaxf((acc[m][0][j] + bias0) * (1.0f / 3.0f) + 0.5f, 0.0f), 1.0f);
                    float pl = pf[j].x * vi;
                    float ev = pf[j].y * fmaxf(acc[m][1][j] + bias1, 0.0f);
                    float vmv = __expf(acc[m][2][j] + bias2);
                    unsigned pk = (unsigned)f2bf(pl - ev) | ((unsigned)f2bf(vmv) << 16);
                    NVu[(size_t)g * 128 + hcol] = pk;   // [t][s][h]
                }
            }
        }
    }
}

// ---------------- K3: role-split scan with MODE ablation ----------------
// MODE 0: full (real). MODE 1: NV loads replaced by constant. MODE 2: no LDS (const PT, no red/RED).
template<int MODE, int ISC>
__device__ __forceinline__ void scan_body(
    int lane, int s, int half, int b,
    float kp, float ks, float kg, float gp, float gpc, float gL, float kpgl, float qb,
    float r0, float r1, float r2, float r3, float r4, float r5, float r6, float r7,
    float c0, float c1, float c2, float c3, float c4, float c5,
    float c6, float c7, float c8,
    const unsigned* __restrict__ nvbase, const float4* ptlds, float (*red)[68],
    float* __restrict__ outp, float* __restrict__ dmy)
{
    float Sf = 0.f, Ss = 0.f, Sg = 0.f;
    float a0 = 0, a1 = 0, a2 = 0, a3 = 0, a4 = 0, a5 = 0, a6 = 0, a7 = 0;
    float sinkacc = 0.f;
    unsigned A[16], B[16];
    if (MODE != 1) {
#pragma unroll
        for (int i = 0; i < 16; ++i) A[i] = nvbase[(size_t)i * (NSS * 128)];
#pragma unroll
        for (int i = 0; i < 16; ++i) B[i] = nvbase[(size_t)(16 + i) * (NSS * 128)];
    }
    float4 pt[4];
    if (MODE != 2) {
#pragma unroll
        for (int i = 0; i < 4; ++i) pt[i] = ptlds[i];
    }

    auto STEP = [&](int t, unsigned cur) {
        float psv, T1, T2;
        if (MODE != 2) {
            int ps = t & 3;
            psv = pt[ps].x; T1 = pt[ps].y; T2 = pt[ps].z;
            pt[ps] = ptlds[t + 4];
        } else { psv = 0.25f; T1 = 1.5f; T2 = -0.5f; }
        float net = __builtin_bit_cast(float, cur << 16);
        float vm  = __builtin_bit_cast(float, cur & 0xFFFF0000u);
        float t1v = Sf + psv;
        float qf = fminf(t1v, vm);
        Sf = fmaxf(t1v - vm, 0.0f);
        float H = fmaxf(Ss + qf + net, 0.0f);
        float qp = fmaxf(kp * H - kpgl, 0.0f);
        float qs = ks * fminf(H, gL);
        Ss = H - qp - qs;
        float qso = qs * gpc;
        float qsg = qs * gp;
        float tg2 = Sg + qsg;
        float qg = kg * tg2 + qb;
        Sg = tg2 - qg;
        float val;
        if (ISC) {
            float cp = exp2f(c0 * T1 + c1 * T2 + c2);
            float cs = exp2f(c3 * T1 + c4 * T2 + c5);
            float cg = exp2f(c6 * T1 + c7 * T2 + c8);
            val = qp * cp + qso * cs + qg * cg;
        } else {
            val = qp + qso + qg;
        }
        a0 += val * r0; a1 += val * r1; a2 += val * r2; a3 += val * r3;
        a4 += val * r4; a5 += val * r5; a6 += val * r6; a7 += val * r7;
        if (MODE != 2) red[t & 15][lane] = a0;
        else sinkacc += a0;
        a0 = a1; a1 = a2; a2 = a3; a3 = a4; a4 = a5; a5 = a6; a6 = a7; a7 = 0.0f;
    };

    auto RED = [&](int base) {
        int v = lane >> 2, sub = lane & 3;
        const float4* rp4 = (const float4*)&red[v][0];
        float4 x0 = rp4[sub * 4 + 0];
        float4 x1 = rp4[sub * 4 + 1];
        float4 x2 = rp4[sub * 4 + 2];
        float4 x3 = rp4[sub * 4 + 3];
        float sA = (x0.x + x0.y) + (x0.z + x0.w);
        float sB = (x1.x + x1.y) + (x1.z + x1.w);
        float sC = (x2.x + x2.y) + (x2.z + x2.w);
        float sD = (x3.x + x3.y) + (x3.z + x3.w);
        float sm = (sA + sB) + (sC + sD);
        sm += __shfl_xor(sm, 1);
        sm += __shfl_xor(sm, 2);
        int tt = base + v;
        if (sub == 0 && tt < NTT)
            outp[((size_t)tt * NSS + s) * 2 + half] = sm;
    };

    for (int tb = 0; tb < 384; tb += 32) {
#pragma unroll
        for (int u = 0; u < 16; ++u) {
            unsigned cur = (MODE == 1) ? 0x3F803F80u : A[u];
            if (MODE != 1) A[u] = nvbase[(size_t)(tb + u + 32) * (NSS * 128)];
            STEP(tb + u, cur);
        }
        if (MODE != 2) RED(tb);
#pragma unroll
        for (int u = 0; u < 16; ++u) {
            unsigned cur = (MODE == 1) ? 0x3F803F80u : B[u];
            if (MODE != 1) B[u] = nvbase[(size_t)(tb + u + 48) * (NSS * 128)];
            STEP(tb + 16 + u, cur);
        }
        if (MODE != 2) RED(tb + 16);
    }
    if (MODE == 2)
        dmy[(size_t)b * 64 + lane] =
            sinkacc + Sf + Ss + Sg + a0 + a1 + a2 + a3 + a4 + a5 + a6;
}

template<int MODE>
__global__ __launch_bounds__(64) void k_scan(
    const float* __restrict__ wsite, const float* __restrict__ rsite,
    const float* __restrict__ gaw,
    const float* __restrict__ ctp8, const float* __restrict__ ctpb,
    const float4* __restrict__ PTg, const unsigned* __restrict__ NVu,
    float* __restrict__ pQ, float* __restrict__ pC, float* __restrict__ dmy)
{
    __shared__ float4 ptlds[TROWS];
    __shared__ __align__(16) float red[16][68];
    int lane = threadIdx.x;
    int b = blockIdx.x;
    int lo = b & 7, q = b >> 3;
    int s = (q >> 2) * 8 + lo;      // site; 4 blocks of a site share b mod 8 (same XCD)
    int hr = q & 3;
    int half = hr >> 1, role = hr & 1;
    if (s >= NSS) return;
    int h = half * 64 + lane;

    if (MODE != 2)
        for (int t = lane; t < TROWS; t += 64) ptlds[t] = PTg[(size_t)t * NSS + s];

    const float* wrow = wsite + s * 896;
    float kp = sigf(wrow[0 * 128 + h]);
    float ks = sigf(wrow[1 * 128 + h]);
    float kg = sigf(wrow[2 * 128 + h]);
    float gp = sigf(wrow[3 * 128 + h]);
    float gpc = 1.0f - gp;
    float gL = __expf(wrow[4 * 128 + h]) * 2.0f;
    float kpgl = kp * gL;
    float qb = fmaxf(wrow[5 * 128 + h], 0.0f);
    float ga = gaw[s * 128 + h];
    float4 rrA = *(const float4*)(rsite + s * 1024 + h * 8);
    float4 rrB = *(const float4*)(rsite + s * 1024 + h * 8 + 4);
    float r0 = fmaxf(rrA.x, 0.0f) * ga;
    float r1 = fmaxf(rrA.y, 0.0f) * ga;
    float r2 = fmaxf(rrA.z, 0.0f) * ga;
    float r3 = fmaxf(rrA.w, 0.0f) * ga;
    float r4 = fmaxf(rrB.x, 0.0f) * ga;
    float r5 = fmaxf(rrB.y, 0.0f) * ga;
    float r6 = fmaxf(rrB.z, 0.0f) * ga;
    float r7 = fmaxf(rrB.w, 0.0f) * ga;

    const unsigned* nvbase = NVu + (size_t)s * 128 + h;

    if (role == 0) {
        scan_body<MODE, 0>(lane, s, half, b, kp, ks, kg, gp, gpc, gL, kpgl, qb,
                           r0, r1, r2, r3, r4, r5, r6, r7,
                           0.f, 0.f, 0.f, 0.f, 0.f, 0.f, 0.f, 0.f, 0.f,
                           nvbase, ptlds, red, pQ, dmy);
    } else {
        const float4* cp4 = (const float4*)(ctp8 + ((size_t)s * 128 + h) * 8);
        float4 cA = cp4[0], cB = cp4[1];
        float cgb = ctpb[(size_t)s * 128 + h];
        scan_body<MODE, 1>(lane, s, half, b, kp, ks, kg, gp, gpc, gL, kpgl, qb,
                           r0, r1, r2, r3, r4, r5, r6, r7,
                           cA.x, cA.y, cA.z, cA.w, cB.x, cB.y, cB.z, cB.w, cgb,
                           nvbase, ptlds, red, pC, dmy);
    }
}

// ---------------- K4: combine halves, divide ----------------
__global__ __launch_bounds__(256) void k_final(const float* __restrict__ pQ,
                                               const float* __restrict__ pC,
                                               float* __restrict__ out)
{
    int i = blockIdx.x * 256 + threadIdx.x;
    if (i < NROWS) {
        float q = pQ[i * 2] + pQ[i * 2 + 1];
        float c = pC[i * 2] + pC[i * 2 + 1];
        out[i] = q;
        out[NROWS + i] = c / q;
    }
}

extern "C" void kernel_launch(void* const* d_in, const int* in_sizes, int n_in,
                              void* d_out, int out_size, void* d_ws, size_t ws_size,
                              hipStream_t stream)
{
    const float* x      = (const float*)d_in[0];
    const float* xc     = (const float*)d_in[1];
    const float* fcR_w1 = (const float*)d_in[2];
    const float* fcR_b1 = (const float*)d_in[3];
    const float* fcR_w2 = (const float*)d_in[4];
    const float* fcR_b2 = (const float*)d_in[5];
    const float* fcW_w1 = (const float*)d_in[6];
    const float* fcW_b1 = (const float*)d_in[7];
    const float* fcW_w2 = (const float*)d_in[8];
    const float* fcW_b2 = (const float*)d_in[9];
    const float* fcT_w1 = (const float*)d_in[10];
    const float* fcT_b1 = (const float*)d_in[11];
    const float* fcT_w2 = (const float*)d_in[12];
    const float* fcT_b2 = (const float*)d_in[13];
    const float* fcCT_w = (const float*)d_in[14];
    const float* fcCT_b = (const float*)d_in[15];
    float* out = (float*)d_out;

    float* ws = (float*)d_ws;
    size_t o_w    = 0;                                     // 268800
    size_t o_r    = o_w   + 300 * 896;                     // 307200
    size_t o_ga   = o_r   + 300 * 1024;                    // 38400
    size_t o_PT   = o_ga  + 300 * 128;                     // TROWS*NSS float4
    size_t o_NV   = o_PT  + (size_t)TROWS * NSS * 4;       // TROWS*NSS*128 u32
    size_t o_pQ   = o_NV  + (size_t)TROWS * NSS * 128;     // NROWS*2
    size_t o_pC   = o_pQ  + (size_t)NROWS * 2;
    size_t o_pQd  = o_pC  + (size_t)NROWS * 2;             // dummy outs (MODE1)
    size_t o_pCd  = o_pQd + (size_t)NROWS * 2;
    size_t o_dmy  = o_pCd + (size_t)NROWS * 2;             // 1216*64 (MODE2)
    size_t o_w1bf = o_dmy + 1216 * 64;
    size_t o_w2bf = o_w1bf + 8192;
    size_t o_ctp  = o_w2bf + 49152;
    size_t o_ctpb = o_ctp  + (size_t)300 * 128 * 8;

    float* wsite = ws + o_w;
    float* rsite = ws + o_r;
    float* gaw   = ws + o_ga;
    float4* PT   = (float4*)(ws + o_PT);
    unsigned* NVu = (unsigned*)(ws + o_NV);
    float* pQ    = ws + o_pQ;
    float* pC    = ws + o_pC;
    float* pQd   = ws + o_pQd;
    float* pCd   = ws + o_pCd;
    float* dmy   = ws + o_dmy;
    unsigned short* w1s = (unsigned short*)(ws + o_w1bf);
    unsigned short* w2s = (unsigned short*)(ws + o_w2bf);
    float* ctp8  = ws + o_ctp;
    float* ctpb  = ws + o_ctpb;

    k_prep<<<56, 256, 0, stream>>>(fcT_w1, fcT_w2, w1s, w2s);
    k_site<<<dim3(30, 8), 256, 0, stream>>>(xc, fcW_w1, fcW_b1, fcW_w2, fcW_b2,
                                            fcR_w1, fcR_b1, fcR_w2, fcR_b2, wsite, rsite);
    k_softmax_ga<<<300, 128, 0, stream>>>(wsite, gaw);
    k_ct<<<300, 128, 0, stream>>>(xc, fcCT_w, fcCT_b, ctp8, ctpb);
    int nblk2 = (NROWS + 63) / 64;   // 1711
    k_fcT<<<nblk2, 512, 0, stream>>>(x, xc, w1s, fcT_b1, w2s, fcT_b2, PT, NVu);
    // real pass
    k_scan<0><<<1216, 64, 0, stream>>>(wsite, rsite, gaw, ctp8, ctpb,
                                       PT, NVu, pQ, pC, dmy);
    // ablations (write to scratch only; per-dispatch rocprof rows are the data)
    k_scan<1><<<1216, 64, 0, stream>>>(wsite, rsite, gaw, ctp8, ctpb,
                                       PT, NVu, pQd, pCd, dmy);
    k_scan<2><<<1216, 64, 0, stream>>>(wsite, rsite, gaw, ctp8, ctpb,
                                       PT, NVu, pQd, pCd, dmy);
    k_final<<<(NROWS + 255) / 256, 256, 0, stream>>>(pQ, pC, out);
}

// Round 12
// 170.237 us; speedup vs baseline: 1.7725x; 1.7725x over previous
//
#include <hip/hip_runtime.h>
#include <math.h>

#define NTT 365
#define NSS 300
#define NROWS (NTT*NSS)   // 109500
#define TROWS 416         // padded time rows for PT and NV
#define SEGB 176          // segment-1 start (warmup 176..191, outputs from 192)

using bf16x8 = __attribute__((ext_vector_type(8))) short;
using f32x4  = __attribute__((ext_vector_type(4))) float;

__device__ __forceinline__ float sigf(float v) { return 1.0f / (1.0f + __expf(-v)); }

__device__ __forceinline__ float tanhfast(float x) {
    float e = __expf(2.0f * x);
    return 1.0f - 2.0f * __builtin_amdgcn_rcpf(1.0f + e);
}

__device__ __forceinline__ unsigned short f2bf(float f) {
    unsigned u = __builtin_bit_cast(unsigned, f);
    u += 0x7FFFu + ((u >> 16) & 1u);
    return (unsigned short)(u >> 16);
}

// ---------------- K0: swizzle fcT weights to fragment-major bf16 ----------------
__global__ __launch_bounds__(256) void k_prep(const float* __restrict__ w1,
                                              const float* __restrict__ w2,
                                              unsigned short* __restrict__ w1s,
                                              unsigned short* __restrict__ w2s)
{
    int G = blockIdx.x * 256 + threadIdx.x;
    if (G < 2048) {
        int lane = G & 63, ks = (G >> 6) & 1, tile = G >> 7;
        int o = tile * 16 + (lane & 15);
        int kb = ks * 32 + (lane >> 4) * 8;
        unsigned short tmp[8];
#pragma unroll
        for (int e = 0; e < 8; ++e) {
            int k = kb + e;
            tmp[e] = (k < 38) ? f2bf(w1[o * 38 + k]) : (unsigned short)0;
        }
        *(bf16x8*)(w1s + (size_t)G * 8) = *(bf16x8*)tmp;
    } else if (G < 2048 + 12288) {
        int G2 = G - 2048;
        int lane = G2 & 63, ks = (G2 >> 6) & 7, tile = G2 >> 9;
        int o = tile * 16 + (lane & 15);
        int kb = ks * 32 + (lane >> 4) * 8;
        unsigned short tmp[8];
#pragma unroll
        for (int e = 0; e < 8; ++e) tmp[e] = f2bf(w2[o * 256 + kb + e]);
        *(bf16x8*)(w2s + (size_t)G2 * 8) = *(bf16x8*)tmp;
    }
}

// ---------------- K1: per-site MLPs, output-sliced grid (30 x 8) ----------------
__global__ __launch_bounds__(256) void k_site(
    const float* __restrict__ xc,
    const float* __restrict__ wW1, const float* __restrict__ bW1,
    const float* __restrict__ wW2, const float* __restrict__ bW2,
    const float* __restrict__ wR1, const float* __restrict__ bR1,
    const float* __restrict__ wR2, const float* __restrict__ bR2,
    float* __restrict__ wsite, float* __restrict__ rsite)
{
    __shared__ float xcb[10][32];
    __shared__ float hW[10][256];
    __shared__ float hR[10][256];
    int tid = threadIdx.x;
    int s0 = blockIdx.x * 10;
    int os = blockIdx.y;
    for (int i = tid; i < 10 * 32; i += 256) xcb[i / 32][i % 32] = xc[s0 * 32 + i];
    __syncthreads();
    {
        int j = tid;
        float aW[10], aR[10];
#pragma unroll
        for (int r = 0; r < 10; ++r) { aW[r] = bW1[j]; aR[r] = bR1[j]; }
        for (int k = 0; k < 32; ++k) {
            float wv = wW1[j * 32 + k], rv = wR1[j * 32 + k];
#pragma unroll
            for (int r = 0; r < 10; ++r) { float xv = xcb[r][k]; aW[r] += xv * wv; aR[r] += xv * rv; }
        }
#pragma unroll
        for (int r = 0; r < 10; ++r) { hW[r][j] = tanhfast(aW[r]); hR[r][j] = tanhfast(aR[r]); }
    }
    __syncthreads();
    if (tid < 240) {
        int o_lin = os * 240 + tid;
        float acc[10];
        if (o_lin < 896) {
            int o = o_lin;
#pragma unroll
            for (int r = 0; r < 10; ++r) acc[r] = bW2[o];
            for (int k = 0; k < 256; ++k) {
                float wv = wW2[o * 256 + k];
#pragma unroll
                for (int r = 0; r < 10; ++r) acc[r] += hW[r][k] * wv;
            }
#pragma unroll
            for (int r = 0; r < 10; ++r) wsite[(s0 + r) * 896 + o] = acc[r];
        } else {
            int o = o_lin - 896;
#pragma unroll
            for (int r = 0; r < 10; ++r) acc[r] = bR2[o];
            for (int k = 0; k < 256; ++k) {
                float wv = wR2[o * 256 + k];
#pragma unroll
                for (int r = 0; r < 10; ++r) acc[r] += hR[r][k] * wv;
            }
#pragma unroll
            for (int r = 0; r < 10; ++r) rsite[(s0 + r) * 1024 + o] = acc[r];
        }
    }
}

// ---------------- K1b: softmax of ga over h per site ----------------
__global__ __launch_bounds__(128) void k_softmax_ga(const float* __restrict__ wsite,
                                                    float* __restrict__ ga)
{
    int s = blockIdx.x, tid = threadIdx.x;
    __shared__ float red[2];
    float v = wsite[s * 896 + 6 * 128 + tid];
    float m = v;
#pragma unroll
    for (int off = 32; off >= 1; off >>= 1) m = fmaxf(m, __shfl_xor(m, off));
    if ((tid & 63) == 0) red[tid >> 6] = m;
    __syncthreads();
    m = fmaxf(red[0], red[1]);
    __syncthreads();
    float e = __expf(v - m);
    float ssum = e;
#pragma unroll
    for (int off = 32; off >= 1; off >>= 1) ssum += __shfl_xor(ssum, off);
    if ((tid & 63) == 0) red[tid >> 6] = ssum;
    __syncthreads();
    ssum = red[0] + red[1];
    ga[s * 128 + tid] = e / ssum;
}

// ---------------- K1c: precompute ct gate params per (s,h) ----------------
__global__ __launch_bounds__(128) void k_ct(const float* __restrict__ xc,
                                            const float* __restrict__ ctw,
                                            const float* __restrict__ ctb,
                                            float* __restrict__ ctp8,
                                            float* __restrict__ ctpb)
{
    __shared__ float xcs[32];
    int s = blockIdx.x, h = threadIdx.x;
    if (h < 32) xcs[h] = xc[s * 32 + h];
    __syncthreads();
    const float L2E = 1.4426950408889634f;
    const float LG01 = -3.3219280948873623f;
    float out[8];
    float cgb = 0.0f;
#pragma unroll
    for (int g = 0; g < 3; ++g) {
        const float* wr = ctw + (g * 128 + h) * 34;
        float base = ctb[g * 128 + h];
        for (int k = 0; k < 32; ++k) base += wr[2 + k] * xcs[k];
        float w0 = wr[0] * L2E, w1 = wr[1] * L2E;
        float bb = base * L2E + ((g == 0) ? LG01 : 0.0f);
        if (g == 0) { out[0] = w0; out[1] = w1; out[2] = bb; }
        else if (g == 1) { out[3] = w0; out[4] = w1; out[5] = bb; }
        else { out[6] = w0; out[7] = w1; cgb = bb; }
    }
    float4* dst = (float4*)(ctp8 + ((size_t)s * 128 + h) * 8);
    dst[0] = make_float4(out[0], out[1], out[2], out[3]);
    dst[1] = make_float4(out[4], out[5], out[6], out[7]);
    ctpb[(size_t)s * 128 + h] = cgb;
}

// ---------------- K2: fcT MLP via bf16 MFMA -> PT[g] ([t][s]), NVu[t][s][h] ----------------
__global__ __launch_bounds__(512) void k_fcT(
    const float* __restrict__ x, const float* __restrict__ xc,
    const unsigned short* __restrict__ w1s, const float* __restrict__ b1,
    const unsigned short* __restrict__ w2s, const float* __restrict__ b2,
    float4* __restrict__ PT, unsigned* __restrict__ NVu)
{
    __shared__ unsigned short A1[64][72];
    __shared__ unsigned short hb[64][264];
    __shared__ float2 pfE[64];
    int tid = threadIdx.x;
    int row0 = blockIdx.x * 64;

    for (int idx = tid; idx < 64 * 64; idx += 512) {
        int r = idx >> 6, c = idx & 63;
        int g = row0 + r;
        float val = 0.0f;
        if (g < NROWS) {
            if (c < 6) val = x[g * 6 + c];
            else if (c < 38) { int s = g % NSS; val = xc[s * 32 + (c - 6)]; }
        }
        A1[r][c] = f2bf(val);
    }
    if (tid < 64) {
        int r = tid, g = row0 + r;
        float P = 0, E = 0, T1 = 0, T2 = 0;
        if (g < NROWS) { P = x[g * 6]; E = x[g * 6 + 1]; T1 = x[g * 6 + 2]; T2 = x[g * 6 + 3]; }
        float den = T2 - T1;
        float dg = (den == 0.0f) ? 1.0f : den;
        float ratio = fminf(fmaxf((T1 + T2) / dg, -1.0f), 1.0f);
        float vf = acosf(ratio) * (1.0f / 3.1415f);
        vf = (T1 >= 0.0f) ? 0.0f : ((T2 <= 0.0f) ? 1.0f : vf);
        pfE[r] = make_float2(P * (1.0f - vf), 2.0f * E);
        if (g < NROWS) PT[g] = make_float4(P * vf, T1, T2, vf);
    }
    __syncthreads();

    int lane = tid & 63, wv = tid >> 6;
    int r16 = lane & 15;
    int kg = (lane >> 4) * 8;
    int rq = (lane >> 4) * 4;

    {
        int mt = wv & 3, nb = (wv >> 2) * 8;
        f32x4 acc[8];
#pragma unroll
        for (int i = 0; i < 8; ++i) acc[i] = (f32x4){0.f, 0.f, 0.f, 0.f};
#pragma unroll
        for (int ks = 0; ks < 2; ++ks) {
            bf16x8 a = *(const bf16x8*)&A1[mt * 16 + r16][ks * 32 + kg];
#pragma unroll
            for (int i = 0; i < 8; ++i) {
                bf16x8 b = *(const bf16x8*)(w1s + ((size_t)(((nb + i) * 2 + ks) * 64 + lane) << 3));
                acc[i] = __builtin_amdgcn_mfma_f32_16x16x32_bf16(a, b, acc[i], 0, 0, 0);
            }
        }
#pragma unroll
        for (int i = 0; i < 8; ++i) {
            int col = (nb + i) * 16 + r16;
            float bias = b1[col];
#pragma unroll
            for (int j = 0; j < 4; ++j) {
                int row = mt * 16 + rq + j;
                hb[row][col] = f2bf(tanhfast(acc[i][j] + bias));
            }
        }
    }
    __syncthreads();

    {
        int t0 = wv, t1 = wv + 8, t2 = wv + 16;
        f32x4 acc[4][3];
#pragma unroll
        for (int m = 0; m < 4; ++m)
#pragma unroll
            for (int c = 0; c < 3; ++c) acc[m][c] = (f32x4){0.f, 0.f, 0.f, 0.f};
#pragma unroll
        for (int ks = 0; ks < 8; ++ks) {
            bf16x8 b0 = *(const bf16x8*)(w2s + ((size_t)((t0 * 8 + ks) * 64 + lane) << 3));
            bf16x8 b1v = *(const bf16x8*)(w2s + ((size_t)((t1 * 8 + ks) * 64 + lane) << 3));
            bf16x8 b2v = *(const bf16x8*)(w2s + ((size_t)((t2 * 8 + ks) * 64 + lane) << 3));
#pragma unroll
            for (int m = 0; m < 4; ++m) {
                bf16x8 a = *(const bf16x8*)&hb[m * 16 + r16][ks * 32 + kg];
                acc[m][0] = __builtin_amdgcn_mfma_f32_16x16x32_bf16(a, b0, acc[m][0], 0, 0, 0);
                acc[m][1] = __builtin_amdgcn_mfma_f32_16x16x32_bf16(a, b1v, acc[m][1], 0, 0, 0);
                acc[m][2] = __builtin_amdgcn_mfma_f32_16x16x32_bf16(a, b2v, acc[m][2], 0, 0, 0);
            }
        }
        int hcol = wv * 16 + r16;
        float bias0 = b2[hcol], bias1 = b2[128 + hcol], bias2 = b2[256 + hcol];
#pragma unroll
        for (int m = 0; m < 4; ++m) {
            float2 pf[4];
#pragma unroll
            for (int j = 0; j < 4; ++j) pf[j] = pfE[m * 16 + rq + j];
#pragma unroll
            for (int j = 0; j < 4; ++j) {
                int r = m * 16 + rq + j;
                int g = row0 + r;
                if (g < NROWS) {
                    float vi = fminf(fmaxf((acc[m][0][j] + bias0) * (1.0f / 3.0f) + 0.5f, 0.0f), 1.0f);
                    float pl = pf[j].x * vi;
                    float ev = pf[j].y * fmaxf(acc[m][1][j] + bias1, 0.0f);
                    float vmv = __expf(acc[m][2][j] + bias2);
                    unsigned pk = (unsigned)f2bf(pl - ev) | ((unsigned)f2bf(vmv) << 16);
                    NVu[(size_t)g * 128 + hcol] = pk;   // [t][s][h]
                }
            }
        }
    }
}

// ---------------- K3a: carry pass — recurrence only, t=0..SEGB-1, checkpoint state ----------------
__global__ __launch_bounds__(64) __attribute__((amdgpu_waves_per_eu(1, 2)))
void k_carry(const float* __restrict__ wsite,
             const float4* __restrict__ PTg, const unsigned* __restrict__ NVu,
             float4* __restrict__ chk)
{
    __shared__ float psl[192];
    int lane = threadIdx.x;
    int b = blockIdx.x;
    int lo = b & 7, q = b >> 3;
    int s = (q >> 1) * 8 + lo;
    int half = q & 1;
    if (s >= NSS) return;
    int h = half * 64 + lane;

    for (int t = lane; t < 192; t += 64) psl[t] = PTg[(size_t)t * NSS + s].x;

    const float* wrow = wsite + s * 896;
    float kp = sigf(wrow[0 * 128 + h]);
    float ks = sigf(wrow[1 * 128 + h]);
    float kg = sigf(wrow[2 * 128 + h]);
    float gp = sigf(wrow[3 * 128 + h]);
    float gL = __expf(wrow[4 * 128 + h]) * 2.0f;
    float kpgl = kp * gL;
    float qb = fmaxf(wrow[5 * 128 + h], 0.0f);

    const unsigned* nvbase = NVu + (size_t)s * 128 + h;
    unsigned A[16];
#pragma unroll
    for (int i = 0; i < 16; ++i) A[i] = nvbase[(size_t)i * (NSS * 128)];

    float Sf = 0.f, Ss = 0.f, Sg = 0.f;
    for (int tb = 0; tb < SEGB; tb += 16) {
#pragma unroll
        for (int u = 0; u < 16; ++u) {
            int t = tb + u;
            unsigned cur = A[u];
            A[u] = nvbase[(size_t)(t + 16) * (NSS * 128)];
            float psv = psl[t];
            float net = __builtin_bit_cast(float, cur << 16);
            float vm  = __builtin_bit_cast(float, cur & 0xFFFF0000u);
            float t1v = Sf + psv;
            float qf = fminf(t1v, vm);
            Sf = fmaxf(t1v - vm, 0.0f);
            float H = fmaxf(Ss + qf + net, 0.0f);
            float qp = fmaxf(kp * H - kpgl, 0.0f);
            float qs = ks * fminf(H, gL);
            Ss = H - qp - qs;
            float qsg = qs * gp;
            float tg2 = Sg + qsg;
            float qg = kg * tg2 + qb;
            Sg = tg2 - qg;
        }
        asm volatile("" ::: "memory");
    }
    chk[(size_t)s * 128 + h] = make_float4(Sf, Ss, Sg, 0.0f);
}

// ---------------- K3b: segmented role-split scan ----------------
template<int ISC>
__device__ __forceinline__ void scan_body(
    int lane, int s, int half, int t0, int redFirst, float4 st0,
    float kp, float ks, float kg, float gp, float gpc, float gL, float kpgl, float qb,
    float r0, float r1, float r2, float r3, float r4, float r5, float r6, float r7,
    float c0, float c1, float c2, float c3, float c4, float c5,
    float c6, float c7, float c8,
    const unsigned* __restrict__ nvbase, const float4* ptlds, float (*red)[68],
    float* __restrict__ outp)
{
    float Sf = st0.x, Ss = st0.y, Sg = st0.z;
    float a0 = 0, a1 = 0, a2 = 0, a3 = 0, a4 = 0, a5 = 0, a6 = 0, a7 = 0;
    unsigned A[16], B[16];
#pragma unroll
    for (int i = 0; i < 16; ++i) A[i] = nvbase[(size_t)(t0 + i) * (NSS * 128)];
#pragma unroll
    for (int i = 0; i < 16; ++i) B[i] = nvbase[(size_t)(t0 + 16 + i) * (NSS * 128)];
    float4 pt[4];
#pragma unroll
    for (int i = 0; i < 4; ++i) pt[i] = ptlds[t0 + i];

    auto STEP = [&](int t, unsigned cur) {
        int ps = t & 3;
        float psv = pt[ps].x, T1 = pt[ps].y, T2 = pt[ps].z;
        pt[ps] = ptlds[t + 4];
        float net = __builtin_bit_cast(float, cur << 16);
        float vm  = __builtin_bit_cast(float, cur & 0xFFFF0000u);
        float t1v = Sf + psv;
        float qf = fminf(t1v, vm);
        Sf = fmaxf(t1v - vm, 0.0f);
        float H = fmaxf(Ss + qf + net, 0.0f);
        float qp = fmaxf(kp * H - kpgl, 0.0f);
        float qs = ks * fminf(H, gL);
        Ss = H - qp - qs;
        float qso = qs * gpc;
        float qsg = qs * gp;
        float tg2 = Sg + qsg;
        float qg = kg * tg2 + qb;
        Sg = tg2 - qg;
        float val;
        if (ISC) {
            float cp = exp2f(c0 * T1 + c1 * T2 + c2);
            float cs = exp2f(c3 * T1 + c4 * T2 + c5);
            float cg = exp2f(c6 * T1 + c7 * T2 + c8);
            val = qp * cp + qso * cs + qg * cg;
        } else {
            val = qp + qso + qg;
        }
        a0 += val * r0; a1 += val * r1; a2 += val * r2; a3 += val * r3;
        a4 += val * r4; a5 += val * r5; a6 += val * r6; a7 += val * r7;
        red[t & 15][lane] = a0;
        a0 = a1; a1 = a2; a2 = a3; a3 = a4; a4 = a5; a5 = a6; a6 = a7; a7 = 0.0f;
    };

    auto RED = [&](int base) {
        int v = lane >> 2, sub = lane & 3;
        const float4* rp4 = (const float4*)&red[v][0];
        float4 x0 = rp4[sub * 4 + 0];
        float4 x1 = rp4[sub * 4 + 1];
        float4 x2 = rp4[sub * 4 + 2];
        float4 x3 = rp4[sub * 4 + 3];
        float sA = (x0.x + x0.y) + (x0.z + x0.w);
        float sB = (x1.x + x1.y) + (x1.z + x1.w);
        float sC = (x2.x + x2.y) + (x2.z + x2.w);
        float sD = (x3.x + x3.y) + (x3.z + x3.w);
        float sm = (sA + sB) + (sC + sD);
        sm += __shfl_xor(sm, 1);
        sm += __shfl_xor(sm, 2);
        int tt = base + v;
        if (sub == 0 && tt < NTT)
            outp[((size_t)tt * NSS + s) * 2 + half] = sm;
    };

    for (int tb = 0; tb < 192; tb += 32) {
#pragma unroll
        for (int u = 0; u < 16; ++u) {
            int t = t0 + tb + u;
            unsigned cur = A[u];
            A[u] = nvbase[(size_t)(t + 32) * (NSS * 128)];
            STEP(t, cur);
        }
        asm volatile("" ::: "memory");
        if (redFirst | (tb > 0)) RED(t0 + tb);
#pragma unroll
        for (int u = 0; u < 16; ++u) {
            int t = t0 + tb + 16 + u;
            unsigned cur = B[u];
            B[u] = nvbase[(size_t)(t + 32) * (NSS * 128)];
            STEP(t, cur);
        }
        asm volatile("" ::: "memory");
        RED(t0 + tb + 16);
    }
}

__global__ __launch_bounds__(64) __attribute__((amdgpu_waves_per_eu(2, 4)))
void k_scan(
    const float* __restrict__ wsite, const float* __restrict__ rsite,
    const float* __restrict__ gaw,
    const float* __restrict__ ctp8, const float* __restrict__ ctpb,
    const float4* __restrict__ PTg, const unsigned* __restrict__ NVu,
    const float4* __restrict__ chk,
    float* __restrict__ pQ, float* __restrict__ pC)
{
    __shared__ float4 ptlds[TROWS];
    __shared__ __align__(16) float red[16][68];
    int lane = threadIdx.x;
    int b = blockIdx.x;
    int lo = b & 7, q = b >> 3;
    int s = (q >> 3) * 8 + lo;       // site; 8 blocks of a site share b mod 8 (same XCD)
    int half = (q >> 2) & 1;
    int role = (q >> 1) & 1;
    int seg  = q & 1;
    if (s >= NSS) return;
    int h = half * 64 + lane;

    for (int t = lane; t < TROWS; t += 64) ptlds[t] = PTg[(size_t)t * NSS + s];

    const float* wrow = wsite + s * 896;
    float kp = sigf(wrow[0 * 128 + h]);
    float ks = sigf(wrow[1 * 128 + h]);
    float kg = sigf(wrow[2 * 128 + h]);
    float gp = sigf(wrow[3 * 128 + h]);
    float gpc = 1.0f - gp;
    float gL = __expf(wrow[4 * 128 + h]) * 2.0f;
    float kpgl = kp * gL;
    float qb = fmaxf(wrow[5 * 128 + h], 0.0f);
    float ga = gaw[s * 128 + h];
    float4 rrA = *(const float4*)(rsite + s * 1024 + h * 8);
    float4 rrB = *(const float4*)(rsite + s * 1024 + h * 8 + 4);
    float r0 = fmaxf(rrA.x, 0.0f) * ga;
    float r1 = fmaxf(rrA.y, 0.0f) * ga;
    float r2 = fmaxf(rrA.z, 0.0f) * ga;
    float r3 = fmaxf(rrA.w, 0.0f) * ga;
    float r4 = fmaxf(rrB.x, 0.0f) * ga;
    float r5 = fmaxf(rrB.y, 0.0f) * ga;
    float r6 = fmaxf(rrB.z, 0.0f) * ga;
    float r7 = fmaxf(rrB.w, 0.0f) * ga;

    const unsigned* nvbase = NVu + (size_t)s * 128 + h;
    int t0 = seg ? SEGB : 0;
    int redFirst = seg ? 0 : 1;
    float4 st0 = seg ? chk[(size_t)s * 128 + h] : make_float4(0.f, 0.f, 0.f, 0.f);

    if (role == 0) {
        scan_body<0>(lane, s, half, t0, redFirst, st0,
                     kp, ks, kg, gp, gpc, gL, kpgl, qb,
                     r0, r1, r2, r3, r4, r5, r6, r7,
                     0.f, 0.f, 0.f, 0.f, 0.f, 0.f, 0.f, 0.f, 0.f,
                     nvbase, ptlds, red, pQ);
    } else {
        const float4* cp4 = (const float4*)(ctp8 + ((size_t)s * 128 + h) * 8);
        float4 cA = cp4[0], cB = cp4[1];
        float cgb = ctpb[(size_t)s * 128 + h];
        scan_body<1>(lane, s, half, t0, redFirst, st0,
                     kp, ks, kg, gp, gpc, gL, kpgl, qb,
                     r0, r1, r2, r3, r4, r5, r6, r7,
                     cA.x, cA.y, cA.z, cA.w, cB.x, cB.y, cB.z, cB.w, cgb,
                     nvbase, ptlds, red, pC);
    }
}

// ---------------- K4: combine halves, divide ----------------
__global__ __launch_bounds__(256) void k_final(const float* __restrict__ pQ,
                                               const float* __restrict__ pC,
                                               float* __restrict__ out)
{
    int i = blockIdx.x * 256 + threadIdx.x;
    if (i < NROWS) {
        float q = pQ[i * 2] + pQ[i * 2 + 1];
        float c = pC[i * 2] + pC[i * 2 + 1];
        out[i] = q;
        out[NROWS + i] = c / q;
    }
}

extern "C" void kernel_launch(void* const* d_in, const int* in_sizes, int n_in,
                              void* d_out, int out_size, void* d_ws, size_t ws_size,
                              hipStream_t stream)
{
    const float* x      = (const float*)d_in[0];
    const float* xc     = (const float*)d_in[1];
    const float* fcR_w1 = (const float*)d_in[2];
    const float* fcR_b1 = (const float*)d_in[3];
    const float* fcR_w2 = (const float*)d_in[4];
    const float* fcR_b2 = (const float*)d_in[5];
    const float* fcW_w1 = (const float*)d_in[6];
    const float* fcW_b1 = (const float*)d_in[7];
    const float* fcW_w2 = (const float*)d_in[8];
    const float* fcW_b2 = (const float*)d_in[9];
    const float* fcT_w1 = (const float*)d_in[10];
    const float* fcT_b1 = (const float*)d_in[11];
    const float* fcT_w2 = (const float*)d_in[12];
    const float* fcT_b2 = (const float*)d_in[13];
    const float* fcCT_w = (const float*)d_in[14];
    const float* fcCT_b = (const float*)d_in[15];
    float* out = (float*)d_out;

    float* ws = (float*)d_ws;
    size_t o_w    = 0;                                     // 268800
    size_t o_r    = o_w   + 300 * 896;                     // 307200
    size_t o_ga   = o_r   + 300 * 1024;                    // 38400
    size_t o_PT   = o_ga  + 300 * 128;                     // TROWS*NSS float4
    size_t o_NV   = o_PT  + (size_t)TROWS * NSS * 4;       // TROWS*NSS*128 u32
    size_t o_pQ   = o_NV  + (size_t)TROWS * NSS * 128;     // NROWS*2
    size_t o_pC   = o_pQ  + (size_t)NROWS * 2;
    size_t o_chk  = o_pC  + (size_t)NROWS * 2;             // 300*128 float4
    size_t o_w1bf = o_chk + (size_t)300 * 128 * 4;
    size_t o_w2bf = o_w1bf + 8192;
    size_t o_ctp  = o_w2bf + 49152;
    size_t o_ctpb = o_ctp  + (size_t)300 * 128 * 8;

    float* wsite = ws + o_w;
    float* rsite = ws + o_r;
    float* gaw   = ws + o_ga;
    float4* PT   = (float4*)(ws + o_PT);
    unsigned* NVu = (unsigned*)(ws + o_NV);
    float* pQ    = ws + o_pQ;
    float* pC    = ws + o_pC;
    float4* chk  = (float4*)(ws + o_chk);
    unsigned short* w1s = (unsigned short*)(ws + o_w1bf);
    unsigned short* w2s = (unsigned short*)(ws + o_w2bf);
    float* ctp8  = ws + o_ctp;
    float* ctpb  = ws + o_ctpb;

    k_prep<<<56, 256, 0, stream>>>(fcT_w1, fcT_w2, w1s, w2s);
    k_site<<<dim3(30, 8), 256, 0, stream>>>(xc, fcW_w1, fcW_b1, fcW_w2, fcW_b2,
                                            fcR_w1, fcR_b1, fcR_w2, fcR_b2, wsite, rsite);
    k_softmax_ga<<<300, 128, 0, stream>>>(wsite, gaw);
    k_ct<<<300, 128, 0, stream>>>(xc, fcCT_w, fcCT_b, ctp8, ctpb);
    int nblk2 = (NROWS + 63) / 64;   // 1711
    k_fcT<<<nblk2, 512, 0, stream>>>(x, xc, w1s, fcT_b1, w2s, fcT_b2, PT, NVu);
    // carry: 300 sites x 2 halves, XCD-grouped; 38*16 = 608 blocks
    k_carry<<<608, 64, 0, stream>>>(wsite, PT, NVu, chk);
    // main: 300 sites x {half, role, seg}; 38*64 = 2432 blocks
    k_scan<<<2432, 64, 0, stream>>>(wsite, rsite, gaw, ctp8, ctpb,
                                    PT, NVu, chk, pQ, pC);
    k_final<<<(NROWS + 255) / 256, 256, 0, stream>>>(pQ, pC, out);
}

// Round 13
// 169.118 us; speedup vs baseline: 1.7843x; 1.0066x over previous
//
#include <hip/hip_runtime.h>
#include <math.h>

#define NTT 365
#define NSS 300
#define NROWS (NTT*NSS)   // 109500
#define TROWS 416         // padded time rows for PT and NV2
#define NCHK 7            // checkpoints at t=39+48k, k=0..6

using bf16x8 = __attribute__((ext_vector_type(8))) short;
using f32x4  = __attribute__((ext_vector_type(4))) float;

__device__ __forceinline__ float sigf(float v) { return 1.0f / (1.0f + __expf(-v)); }

__device__ __forceinline__ float tanhfast(float x) {
    float e = __expf(2.0f * x);
    return 1.0f - 2.0f * __builtin_amdgcn_rcpf(1.0f + e);
}

__device__ __forceinline__ unsigned short f2bf(float f) {
    unsigned u = __builtin_bit_cast(unsigned, f);
    u += 0x7FFFu + ((u >> 16) & 1u);
    return (unsigned short)(u >> 16);
}

// ---------------- K0: swizzle fcT weights to fragment-major bf16 ----------------
__global__ __launch_bounds__(256) void k_prep(const float* __restrict__ w1,
                                              const float* __restrict__ w2,
                                              unsigned short* __restrict__ w1s,
                                              unsigned short* __restrict__ w2s)
{
    int G = blockIdx.x * 256 + threadIdx.x;
    if (G < 2048) {
        int lane = G & 63, ks = (G >> 6) & 1, tile = G >> 7;
        int o = tile * 16 + (lane & 15);
        int kb = ks * 32 + (lane >> 4) * 8;
        unsigned short tmp[8];
#pragma unroll
        for (int e = 0; e < 8; ++e) {
            int k = kb + e;
            tmp[e] = (k < 38) ? f2bf(w1[o * 38 + k]) : (unsigned short)0;
        }
        *(bf16x8*)(w1s + (size_t)G * 8) = *(bf16x8*)tmp;
    } else if (G < 2048 + 12288) {
        int G2 = G - 2048;
        int lane = G2 & 63, ks = (G2 >> 6) & 7, tile = G2 >> 9;
        int o = tile * 16 + (lane & 15);
        int kb = ks * 32 + (lane >> 4) * 8;
        unsigned short tmp[8];
#pragma unroll
        for (int e = 0; e < 8; ++e) tmp[e] = f2bf(w2[o * 256 + kb + e]);
        *(bf16x8*)(w2s + (size_t)G2 * 8) = *(bf16x8*)tmp;
    }
}

// ---------------- K1: per-site MLPs, output-sliced grid (30 x 8) ----------------
__global__ __launch_bounds__(256) void k_site(
    const float* __restrict__ xc,
    const float* __restrict__ wW1, const float* __restrict__ bW1,
    const float* __restrict__ wW2, const float* __restrict__ bW2,
    const float* __restrict__ wR1, const float* __restrict__ bR1,
    const float* __restrict__ wR2, const float* __restrict__ bR2,
    float* __restrict__ wsite, float* __restrict__ rsite)
{
    __shared__ float xcb[10][32];
    __shared__ float hW[10][256];
    __shared__ float hR[10][256];
    int tid = threadIdx.x;
    int s0 = blockIdx.x * 10;
    int os = blockIdx.y;
    for (int i = tid; i < 10 * 32; i += 256) xcb[i / 32][i % 32] = xc[s0 * 32 + i];
    __syncthreads();
    {
        int j = tid;
        float aW[10], aR[10];
#pragma unroll
        for (int r = 0; r < 10; ++r) { aW[r] = bW1[j]; aR[r] = bR1[j]; }
        for (int k = 0; k < 32; ++k) {
            float wv = wW1[j * 32 + k], rv = wR1[j * 32 + k];
#pragma unroll
            for (int r = 0; r < 10; ++r) { float xv = xcb[r][k]; aW[r] += xv * wv; aR[r] += xv * rv; }
        }
#pragma unroll
        for (int r = 0; r < 10; ++r) { hW[r][j] = tanhfast(aW[r]); hR[r][j] = tanhfast(aR[r]); }
    }
    __syncthreads();
    if (tid < 240) {
        int o_lin = os * 240 + tid;
        float acc[10];
        if (o_lin < 896) {
            int o = o_lin;
#pragma unroll
            for (int r = 0; r < 10; ++r) acc[r] = bW2[o];
            for (int k = 0; k < 256; ++k) {
                float wv = wW2[o * 256 + k];
#pragma unroll
                for (int r = 0; r < 10; ++r) acc[r] += hW[r][k] * wv;
            }
#pragma unroll
            for (int r = 0; r < 10; ++r) wsite[(s0 + r) * 896 + o] = acc[r];
        } else {
            int o = o_lin - 896;
#pragma unroll
            for (int r = 0; r < 10; ++r) acc[r] = bR2[o];
            for (int k = 0; k < 256; ++k) {
                float wv = wR2[o * 256 + k];
#pragma unroll
                for (int r = 0; r < 10; ++r) acc[r] += hR[r][k] * wv;
            }
#pragma unroll
            for (int r = 0; r < 10; ++r) rsite[(s0 + r) * 1024 + o] = acc[r];
        }
    }
}

// ---------------- K1b: softmax of ga over h per site ----------------
__global__ __launch_bounds__(128) void k_softmax_ga(const float* __restrict__ wsite,
                                                    float* __restrict__ ga)
{
    int s = blockIdx.x, tid = threadIdx.x;
    __shared__ float red[2];
    float v = wsite[s * 896 + 6 * 128 + tid];
    float m = v;
#pragma unroll
    for (int off = 32; off >= 1; off >>= 1) m = fmaxf(m, __shfl_xor(m, off));
    if ((tid & 63) == 0) red[tid >> 6] = m;
    __syncthreads();
    m = fmaxf(red[0], red[1]);
    __syncthreads();
    float e = __expf(v - m);
    float ssum = e;
#pragma unroll
    for (int off = 32; off >= 1; off >>= 1) ssum += __shfl_xor(ssum, off);
    if ((tid & 63) == 0) red[tid >> 6] = ssum;
    __syncthreads();
    ssum = red[0] + red[1];
    ga[s * 128 + tid] = e / ssum;
}

// ---------------- K1c: precompute ct gate params per (s,h) ----------------
__global__ __launch_bounds__(128) void k_ct(const float* __restrict__ xc,
                                            const float* __restrict__ ctw,
                                            const float* __restrict__ ctb,
                                            float* __restrict__ ctp8,
                                            float* __restrict__ ctpb)
{
    __shared__ float xcs[32];
    int s = blockIdx.x, h = threadIdx.x;
    if (h < 32) xcs[h] = xc[s * 32 + h];
    __syncthreads();
    const float L2E = 1.4426950408889634f;
    const float LG01 = -3.3219280948873623f;
    float out[8];
    float cgb = 0.0f;
#pragma unroll
    for (int g = 0; g < 3; ++g) {
        const float* wr = ctw + (g * 128 + h) * 34;
        float base = ctb[g * 128 + h];
        for (int k = 0; k < 32; ++k) base += wr[2 + k] * xcs[k];
        float w0 = wr[0] * L2E, w1 = wr[1] * L2E;
        float bb = base * L2E + ((g == 0) ? LG01 : 0.0f);
        if (g == 0) { out[0] = w0; out[1] = w1; out[2] = bb; }
        else if (g == 1) { out[3] = w0; out[4] = w1; out[5] = bb; }
        else { out[6] = w0; out[7] = w1; cgb = bb; }
    }
    float4* dst = (float4*)(ctp8 + ((size_t)s * 128 + h) * 8);
    dst[0] = make_float4(out[0], out[1], out[2], out[3]);
    dst[1] = make_float4(out[4], out[5], out[6], out[7]);
    ctpb[(size_t)s * 128 + h] = cgb;
}

// ---------------- K2: fcT MLP via bf16 MFMA -> PT[t][s], NV2[s][half][t][64] ----------------
__global__ __launch_bounds__(512) void k_fcT(
    const float* __restrict__ x, const float* __restrict__ xc,
    const unsigned short* __restrict__ w1s, const float* __restrict__ b1,
    const unsigned short* __restrict__ w2s, const float* __restrict__ b2,
    float4* __restrict__ PT, unsigned* __restrict__ NV2)
{
    __shared__ unsigned short A1[64][72];
    __shared__ unsigned short hb[64][264];
    __shared__ float2 pfE[64];
    int tid = threadIdx.x;
    int row0 = blockIdx.x * 64;

    for (int idx = tid; idx < 64 * 64; idx += 512) {
        int r = idx >> 6, c = idx & 63;
        int g = row0 + r;
        float val = 0.0f;
        if (g < NROWS) {
            if (c < 6) val = x[g * 6 + c];
            else if (c < 38) { int s = g % NSS; val = xc[s * 32 + (c - 6)]; }
        }
        A1[r][c] = f2bf(val);
    }
    if (tid < 64) {
        int r = tid, g = row0 + r;
        float P = 0, E = 0, T1 = 0, T2 = 0;
        if (g < NROWS) { P = x[g * 6]; E = x[g * 6 + 1]; T1 = x[g * 6 + 2]; T2 = x[g * 6 + 3]; }
        float den = T2 - T1;
        float dg = (den == 0.0f) ? 1.0f : den;
        float ratio = fminf(fmaxf((T1 + T2) / dg, -1.0f), 1.0f);
        float vf = acosf(ratio) * (1.0f / 3.1415f);
        vf = (T1 >= 0.0f) ? 0.0f : ((T2 <= 0.0f) ? 1.0f : vf);
        pfE[r] = make_float2(P * (1.0f - vf), 2.0f * E);
        if (g < NROWS) PT[g] = make_float4(P * vf, T1, T2, vf);
    }
    __syncthreads();

    int lane = tid & 63, wv = tid >> 6;
    int r16 = lane & 15;
    int kg = (lane >> 4) * 8;
    int rq = (lane >> 4) * 4;

    {
        int mt = wv & 3, nb = (wv >> 2) * 8;
        f32x4 acc[8];
#pragma unroll
        for (int i = 0; i < 8; ++i) acc[i] = (f32x4){0.f, 0.f, 0.f, 0.f};
#pragma unroll
        for (int ks = 0; ks < 2; ++ks) {
            bf16x8 a = *(const bf16x8*)&A1[mt * 16 + r16][ks * 32 + kg];
#pragma unroll
            for (int i = 0; i < 8; ++i) {
                bf16x8 b = *(const bf16x8*)(w1s + ((size_t)(((nb + i) * 2 + ks) * 64 + lane) << 3));
                acc[i] = __builtin_amdgcn_mfma_f32_16x16x32_bf16(a, b, acc[i], 0, 0, 0);
            }
        }
#pragma unroll
        for (int i = 0; i < 8; ++i) {
            int col = (nb + i) * 16 + r16;
            float bias = b1[col];
#pragma unroll
            for (int j = 0; j < 4; ++j) {
                int row = mt * 16 + rq + j;
                hb[row][col] = f2bf(tanhfast(acc[i][j] + bias));
            }
        }
    }
    __syncthreads();

    {
        int t0 = wv, t1 = wv + 8, t2 = wv + 16;
        f32x4 acc[4][3];
#pragma unroll
        for (int m = 0; m < 4; ++m)
#pragma unroll
            for (int c = 0; c < 3; ++c) acc[m][c] = (f32x4){0.f, 0.f, 0.f, 0.f};
#pragma unroll
        for (int ks = 0; ks < 8; ++ks) {
            bf16x8 b0 = *(const bf16x8*)(w2s + ((size_t)((t0 * 8 + ks) * 64 + lane) << 3));
            bf16x8 b1v = *(const bf16x8*)(w2s + ((size_t)((t1 * 8 + ks) * 64 + lane) << 3));
            bf16x8 b2v = *(const bf16x8*)(w2s + ((size_t)((t2 * 8 + ks) * 64 + lane) << 3));
#pragma unroll
            for (int m = 0; m < 4; ++m) {
                bf16x8 a = *(const bf16x8*)&hb[m * 16 + r16][ks * 32 + kg];
                acc[m][0] = __builtin_amdgcn_mfma_f32_16x16x32_bf16(a, b0, acc[m][0], 0, 0, 0);
                acc[m][1] = __builtin_amdgcn_mfma_f32_16x16x32_bf16(a, b1v, acc[m][1], 0, 0, 0);
                acc[m][2] = __builtin_amdgcn_mfma_f32_16x16x32_bf16(a, b2v, acc[m][2], 0, 0, 0);
            }
        }
        int hcol = wv * 16 + r16;
        float bias0 = b2[hcol], bias1 = b2[128 + hcol], bias2 = b2[256 + hcol];
#pragma unroll
        for (int m = 0; m < 4; ++m) {
            float2 pf[4];
#pragma unroll
            for (int j = 0; j < 4; ++j) pf[j] = pfE[m * 16 + rq + j];
#pragma unroll
            for (int j = 0; j < 4; ++j) {
                int r = m * 16 + rq + j;
                int g = row0 + r;
                if (g < NROWS) {
                    float vi = fminf(fmaxf((acc[m][0][j] + bias0) * (1.0f / 3.0f) + 0.5f, 0.0f), 1.0f);
                    float pl = pf[j].x * vi;
                    float ev = pf[j].y * fmaxf(acc[m][1][j] + bias1, 0.0f);
                    float vmv = __expf(acc[m][2][j] + bias2);
                    unsigned pk = (unsigned)f2bf(pl - ev) | ((unsigned)f2bf(vmv) << 16);
                    int tg = g / NSS, sg = g - tg * NSS;
                    NV2[((size_t)(sg * 2 + (hcol >> 6)) * TROWS + tg) * 64 + (hcol & 63)] = pk;
                }
            }
        }
    }
}

// ---------------- K3a: carry pass — recurrence only, 328 steps, 7 checkpoints ----------------
__global__ __launch_bounds__(64) void k_carry(
    const float* __restrict__ wsite,
    const float4* __restrict__ PTg, const unsigned* __restrict__ NV2,
    float4* __restrict__ chk)
{
    __shared__ float psl[352];
    int lane = threadIdx.x;
    int b = blockIdx.x;
    int lo = b & 7, q = b >> 3;
    int s = (q >> 1) * 8 + lo;
    int half = q & 1;
    if (s >= NSS) return;
    int h = half * 64 + lane;

    for (int t = lane; t < 352; t += 64) psl[t] = PTg[(size_t)t * NSS + s].x;

    const float* wrow = wsite + s * 896;
    float kp = sigf(wrow[0 * 128 + h]);
    float ks = sigf(wrow[1 * 128 + h]);
    float kg = sigf(wrow[2 * 128 + h]);
    float gp = sigf(wrow[3 * 128 + h]);
    float gL = __expf(wrow[4 * 128 + h]) * 2.0f;
    float kpgl = kp * gL;
    float qb = fmaxf(wrow[5 * 128 + h], 0.0f);

    const unsigned* nvp = NV2 + (size_t)(s * 2 + half) * TROWS * 64 + lane;
    unsigned E[8], O[8];
#pragma unroll
    for (int u = 0; u < 8; ++u) E[u] = nvp[u * 64];
#pragma unroll
    for (int u = 0; u < 8; ++u) O[u] = nvp[(8 + u) * 64];
    const unsigned* pf = nvp + 16 * 64;

    float Sf = 0.f, Ss = 0.f, Sg = 0.f;
    int nxt = 39, ci = 0;

    auto CSTEP = [&](int t, unsigned cur) {
        float psv = psl[t];
        float net = __builtin_bit_cast(float, cur << 16);
        float vm  = __builtin_bit_cast(float, cur & 0xFFFF0000u);
        float t1v = Sf + psv;
        float qf = fminf(t1v, vm);
        Sf = fmaxf(t1v - vm, 0.0f);
        float H = fmaxf(Ss + qf + net, 0.0f);
        float qp = fmaxf(kp * H - kpgl, 0.0f);
        float qs = ks * fminf(H, gL);
        Ss = H - qp - qs;
        float qsg = qs * gp;
        float tg2 = Sg + qsg;
        float qg = kg * tg2 + qb;
        Sg = tg2 - qg;
        if (t == nxt) {
            chk[(size_t)ci * 38400 + (size_t)s * 128 + h] = make_float4(Sf, Ss, Sg, 0.f);
            nxt += 48; ++ci;
        }
    };
    auto CG = [&](unsigned (&X)[8], int tb) {
#pragma unroll
        for (int u = 0; u < 8; ++u) {
            unsigned cur = X[u];
            X[u] = pf[u * 64];
            CSTEP(tb + u, cur);
        }
        pf += 512;
        asm volatile("" ::: "memory");
    };
    int tb = 0;
    for (int p = 0; p < 20; ++p) {
        CG(E, tb); tb += 8;
        CG(O, tb); tb += 8;
    }
    CG(E, tb);   // steps 320..327 (final checkpoint at t=327)
}

// ---------------- K3b: merged-role segmented scan (S=8, 48-step segments) ----------------
__global__ __launch_bounds__(64) void k_scan(
    const float* __restrict__ wsite, const float* __restrict__ rsite,
    const float* __restrict__ gaw,
    const float* __restrict__ ctp8, const float* __restrict__ ctpb,
    const float4* __restrict__ PTg, const unsigned* __restrict__ NV2,
    const float4* __restrict__ chk,
    float* __restrict__ pQ, float* __restrict__ pC)
{
    __shared__ float4 ptl[64];
    __shared__ __align__(16) float red[16][68];
    int lane = threadIdx.x;
    int b = blockIdx.x;
    int lo = b & 7, q = b >> 3;
    int s = (q >> 4) * 8 + lo;        // all 16 (half,seg) blocks of a site share an XCD
    int half = (q >> 3) & 1;
    int seg = q & 7;
    if (s >= NSS) return;
    int h = half * 64 + lane;
    int t0 = seg ? (48 * seg - 8) : 0;

    ptl[lane] = PTg[(size_t)(t0 + lane) * NSS + s];

    const float* wrow = wsite + s * 896;
    float kp = sigf(wrow[0 * 128 + h]);
    float ks = sigf(wrow[1 * 128 + h]);
    float kg = sigf(wrow[2 * 128 + h]);
    float gp = sigf(wrow[3 * 128 + h]);
    float gpc = 1.0f - gp;
    float gL = __expf(wrow[4 * 128 + h]) * 2.0f;
    float kpgl = kp * gL;
    float qb = fmaxf(wrow[5 * 128 + h], 0.0f);
    float ga = gaw[s * 128 + h];
    float4 rrA = *(const float4*)(rsite + s * 1024 + h * 8);
    float4 rrB = *(const float4*)(rsite + s * 1024 + h * 8 + 4);
    float r0 = fmaxf(rrA.x, 0.0f) * ga;
    float r1 = fmaxf(rrA.y, 0.0f) * ga;
    float r2 = fmaxf(rrA.z, 0.0f) * ga;
    float r3 = fmaxf(rrA.w, 0.0f) * ga;
    float r4 = fmaxf(rrB.x, 0.0f) * ga;
    float r5 = fmaxf(rrB.y, 0.0f) * ga;
    float r6 = fmaxf(rrB.z, 0.0f) * ga;
    float r7 = fmaxf(rrB.w, 0.0f) * ga;
    const float4* cp4 = (const float4*)(ctp8 + ((size_t)s * 128 + h) * 8);
    float4 cA = cp4[0], cB = cp4[1];
    float c0 = cA.x, c1 = cA.y, c2 = cA.z, c3 = cA.w;
    float c4 = cB.x, c5 = cB.y, c6 = cB.z, c7 = cB.w;
    float c8 = ctpb[(size_t)s * 128 + h];

    float Sf = 0.f, Ss = 0.f, Sg = 0.f;
    if (seg) {
        float4 st = chk[(size_t)(seg - 1) * 38400 + (size_t)s * 128 + h];
        Sf = st.x; Ss = st.y; Sg = st.z;
    }

    const unsigned* nvp = NV2 + ((size_t)(s * 2 + half) * TROWS + t0) * 64 + lane;
    unsigned E[8], O[8];
#pragma unroll
    for (int u = 0; u < 8; ++u) E[u] = nvp[u * 64];
#pragma unroll
    for (int u = 0; u < 8; ++u) O[u] = nvp[(8 + u) * 64];
    const unsigned* pf = nvp + 16 * 64;

    float4 pt[4];
#pragma unroll
    for (int i = 0; i < 4; ++i) pt[i] = ptl[i];

    float aQ0 = 0, aQ1 = 0, aQ2 = 0, aQ3 = 0, aQ4 = 0, aQ5 = 0, aQ6 = 0, aQ7 = 0;
    float aC0 = 0, aC1 = 0, aC2 = 0, aC3 = 0, aC4 = 0, aC5 = 0, aC6 = 0, aC7 = 0;

    auto STEP = [&](int j, unsigned cur) {
        int ps = j & 3;
        float psv = pt[ps].x, T1 = pt[ps].y, T2 = pt[ps].z;
        pt[ps] = ptl[j + 4];
        float net = __builtin_bit_cast(float, cur << 16);
        float vm  = __builtin_bit_cast(float, cur & 0xFFFF0000u);
        float t1v = Sf + psv;
        float qf = fminf(t1v, vm);
        Sf = fmaxf(t1v - vm, 0.0f);
        float H = fmaxf(Ss + qf + net, 0.0f);
        float qp = fmaxf(kp * H - kpgl, 0.0f);
        float qs = ks * fminf(H, gL);
        Ss = H - qp - qs;
        float qso = qs * gpc;
        float qsg = qs * gp;
        float tg2 = Sg + qsg;
        float qg = kg * tg2 + qb;
        Sg = tg2 - qg;
        float valQ = qp + qso + qg;
        float cpv = exp2f(c0 * T1 + c1 * T2 + c2);
        float csv = exp2f(c3 * T1 + c4 * T2 + c5);
        float cgv = exp2f(c6 * T1 + c7 * T2 + c8);
        float valC = qp * cpv + qso * csv + qg * cgv;
        aQ0 += valQ * r0; aQ1 += valQ * r1; aQ2 += valQ * r2; aQ3 += valQ * r3;
        aQ4 += valQ * r4; aQ5 += valQ * r5; aQ6 += valQ * r6; aQ7 += valQ * r7;
        aC0 += valC * r0; aC1 += valC * r1; aC2 += valC * r2; aC3 += valC * r3;
        aC4 += valC * r4; aC5 += valC * r5; aC6 += valC * r6; aC7 += valC * r7;
        red[j & 7][lane] = aQ0;
        red[8 + (j & 7)][lane] = aC0;
        aQ0 = aQ1; aQ1 = aQ2; aQ2 = aQ3; aQ3 = aQ4; aQ4 = aQ5; aQ5 = aQ6; aQ6 = aQ7; aQ7 = 0.0f;
        aC0 = aC1; aC1 = aC2; aC2 = aC3; aC3 = aC4; aC4 = aC5; aC5 = aC6; aC6 = aC7; aC7 = 0.0f;
    };

    auto RED = [&](int tb) {
        int v = lane >> 2, sub = lane & 3;
        const float4* rp4 = (const float4*)&red[v][0];
        float4 x0 = rp4[sub * 4 + 0];
        float4 x1 = rp4[sub * 4 + 1];
        float4 x2 = rp4[sub * 4 + 2];
        float4 x3 = rp4[sub * 4 + 3];
        float sA = (x0.x + x0.y) + (x0.z + x0.w);
        float sB = (x1.x + x1.y) + (x1.z + x1.w);
        float sC = (x2.x + x2.y) + (x2.z + x2.w);
        float sD = (x3.x + x3.y) + (x3.z + x3.w);
        float sm = (sA + sB) + (sC + sD);
        sm += __shfl_xor(sm, 1);
        sm += __shfl_xor(sm, 2);
        int tt = t0 + tb + (v & 7);
        if (sub == 0 && tt < NTT) {
            float* bp = (v < 8) ? pQ : pC;
            bp[((size_t)tt * NSS + s) * 2 + half] = sm;
        }
    };

    auto GROUP = [&](unsigned (&X)[8], int TB, bool doRed) {
#pragma unroll
        for (int u = 0; u < 8; ++u) {
            unsigned cur = X[u];
            X[u] = pf[u * 64];
            STEP(TB + u, cur);
        }
        pf += 512;
        asm volatile("" ::: "memory");
        if (doRed) RED(TB);
    };

    GROUP(E, 0, seg == 0);   // warmup group for seg>0 (outputs owned by previous seg)
    GROUP(O, 8, true);
    GROUP(E, 16, true);
    GROUP(O, 24, true);
    GROUP(E, 32, true);
    GROUP(O, 40, true);
    if (seg) GROUP(E, 48, true);
}

// ---------------- K4: combine halves, divide ----------------
__global__ __launch_bounds__(256) void k_final(const float* __restrict__ pQ,
                                               const float* __restrict__ pC,
                                               float* __restrict__ out)
{
    int i = blockIdx.x * 256 + threadIdx.x;
    if (i < NROWS) {
        float q = pQ[i * 2] + pQ[i * 2 + 1];
        float c = pC[i * 2] + pC[i * 2 + 1];
        out[i] = q;
        out[NROWS + i] = c / q;
    }
}

extern "C" void kernel_launch(void* const* d_in, const int* in_sizes, int n_in,
                              void* d_out, int out_size, void* d_ws, size_t ws_size,
                              hipStream_t stream)
{
    const float* x      = (const float*)d_in[0];
    const float* xc     = (const float*)d_in[1];
    const float* fcR_w1 = (const float*)d_in[2];
    const float* fcR_b1 = (const float*)d_in[3];
    const float* fcR_w2 = (const float*)d_in[4];
    const float* fcR_b2 = (const float*)d_in[5];
    const float* fcW_w1 = (const float*)d_in[6];
    const float* fcW_b1 = (const float*)d_in[7];
    const float* fcW_w2 = (const float*)d_in[8];
    const float* fcW_b2 = (const float*)d_in[9];
    const float* fcT_w1 = (const float*)d_in[10];
    const float* fcT_b1 = (const float*)d_in[11];
    const float* fcT_w2 = (const float*)d_in[12];
    const float* fcT_b2 = (const float*)d_in[13];
    const float* fcCT_w = (const float*)d_in[14];
    const float* fcCT_b = (const float*)d_in[15];
    float* out = (float*)d_out;

    float* ws = (float*)d_ws;
    size_t o_w    = 0;                                       // 268800
    size_t o_r    = o_w   + 300 * 896;                       // 307200
    size_t o_ga   = o_r   + 300 * 1024;                      // 38400
    size_t o_PT   = o_ga  + 300 * 128;                       // TROWS*NSS float4
    size_t o_NV   = o_PT  + (size_t)TROWS * NSS * 4;         // 300*2*TROWS*64 u32
    size_t o_pQ   = o_NV  + (size_t)300 * 2 * TROWS * 64;    // NROWS*2
    size_t o_pC   = o_pQ  + (size_t)NROWS * 2;
    size_t o_chk  = o_pC  + (size_t)NROWS * 2;               // NCHK*38400 float4
    size_t o_w1bf = o_chk + (size_t)NCHK * 38400 * 4;
    size_t o_w2bf = o_w1bf + 8192;
    size_t o_ctp  = o_w2bf + 49152;
    size_t o_ctpb = o_ctp  + (size_t)300 * 128 * 8;

    float* wsite = ws + o_w;
    float* rsite = ws + o_r;
    float* gaw   = ws + o_ga;
    float4* PT   = (float4*)(ws + o_PT);
    unsigned* NV2 = (unsigned*)(ws + o_NV);
    float* pQ    = ws + o_pQ;
    float* pC    = ws + o_pC;
    float4* chk  = (float4*)(ws + o_chk);
    unsigned short* w1s = (unsigned short*)(ws + o_w1bf);
    unsigned short* w2s = (unsigned short*)(ws + o_w2bf);
    float* ctp8  = ws + o_ctp;
    float* ctpb  = ws + o_ctpb;

    k_prep<<<56, 256, 0, stream>>>(fcT_w1, fcT_w2, w1s, w2s);
    k_site<<<dim3(30, 8), 256, 0, stream>>>(xc, fcW_w1, fcW_b1, fcW_w2, fcW_b2,
                                            fcR_w1, fcR_b1, fcR_w2, fcR_b2, wsite, rsite);
    k_softmax_ga<<<300, 128, 0, stream>>>(wsite, gaw);
    k_ct<<<300, 128, 0, stream>>>(xc, fcCT_w, fcCT_b, ctp8, ctpb);
    int nblk2 = (NROWS + 63) / 64;   // 1711
    k_fcT<<<nblk2, 512, 0, stream>>>(x, xc, w1s, fcT_b1, w2s, fcT_b2, PT, NV2);
    // carry: 300 sites x 2 halves, XCD-grouped; 38*16 = 608 blocks
    k_carry<<<608, 64, 0, stream>>>(wsite, PT, NV2, chk);
    // main: 300 sites x {half, seg0..7}; 38*128 = 4864 blocks
    k_scan<<<4864, 64, 0, stream>>>(wsite, rsite, gaw, ctp8, ctpb,
                                    PT, NV2, chk, pQ, pC);
    k_final<<<(NROWS + 255) / 256, 256, 0, stream>>>(pQ, pC, out);
}